// Round 5
// baseline (1189.552 us; speedup 1.0000x reference)
//
#include <hip/hip_runtime.h>
#include <stdint.h>
#include <math.h>

// Problem constants (from reference):
#define BB 8
#define CC 32
#define TT 3136      // 56*56
#define KK 9
#define OC 64

#define NEGINF (-3.0e38f)
#define BR 32        // rows per block
#define RT 4         // rows per thread
#define MT 8         // col accumulators per thread
#define BC 256       // cols per LDS tile
#define NTILE 13     // 12 full tiles + one 64-col tile
#define CAP 56       // candidate cap per row (P(overflow) ~ 1e-11/row)
#define EPS 1e-4f    // fp32-vs-fp64 + reassociation slack (actual err ~1e-6)

__device__ __forceinline__ uint32_t f2s(float v) {
    uint32_t u = __float_as_uint(v);
    return (u & 0x80000000u) ? ~u : (u | 0x80000000u);
}
__device__ __forceinline__ float s2f(uint32_t u) {
    u = (u & 0x80000000u) ? (u & 0x7FFFFFFFu) : ~u;
    return __uint_as_float(u);
}

// ---------------------------------------------------------------------------
// Kernel 1: transposed copies + norms.
//   xnT[b][t][c] = x[b][c][t] * invn  (fp32 scan)
//   xfT[b][t][c] = x[b][c][t]          (raw, fp64 re-rank + gconv)
//   invn[b][t]   = 1/max(sqrt(sum x^2),1e-12)  (fp64)
// ---------------------------------------------------------------------------
__global__ __launch_bounds__(256) void norm_kernel(
    const float* __restrict__ x, float* __restrict__ xnT,
    float* __restrict__ xfT, double* __restrict__ invn)
{
    int t = blockIdx.x * 256 + threadIdx.x;
    int b = blockIdx.y;
    if (t >= TT) return;
    const float* xp = x + (size_t)b * CC * TT + t;
    float v[CC];
    double ss = 0.0;
#pragma unroll
    for (int c = 0; c < CC; ++c) {
        v[c] = xp[(size_t)c * TT];
        ss = fma((double)v[c], (double)v[c], ss);
    }
    double inv = 1.0 / fmax(sqrt(ss), 1e-12);
    invn[(size_t)b * TT + t] = inv;
    float invf = (float)inv;
    float* pf = xfT + ((size_t)b * TT + t) * CC;
    float* pn = xnT + ((size_t)b * TT + t) * CC;
#pragma unroll
    for (int c = 0; c < CC; c += 4) {
        *(float4*)(pf + c) = make_float4(v[c], v[c+1], v[c+2], v[c+3]);
        *(float4*)(pn + c) = make_float4(v[c]*invf, v[c+1]*invf, v[c+2]*invf, v[c+3]*invf);
    }
}

// ---------------------------------------------------------------------------
// Kernel 2: two-pass top-K with per-thread-max theta.
//   Pass A: fp32 cosine scores; per-thread row maxima (98 disjoint cols each,
//           self-masked). theta[row] = 9th-largest of the 32 thread maxima
//           (9 rounds of shfl argmax+mask) - EPS.
//           Guarantee: >=9 distinct non-self cols score >= theta
//           => all true top-8 >= theta (within EPS of fp64).
//   Pass B: recompute scores; collect cols >= theta into candidx (~10-20).
//   Pass C: fp64 re-rank (exact, verified R2/R3) -> top-8 + self, sorted.
// Block: 256 threads = 8 row-groups(ig) x 32 col-scanners(j).
// Thread computes RT=4 rows x MT=8 cols (j+32m) per 256-col tile.
// ---------------------------------------------------------------------------
__global__ __launch_bounds__(256) void topk_kernel(
    const float* __restrict__ xnT, const float* __restrict__ xfT,
    const double* __restrict__ invn, int* __restrict__ idxo)
{
    __shared__ __align__(16) float colbuf[BC * 36];   // 36.9 KB (pass C: f64 scorebuf)
    __shared__ __align__(16) float rowbuf[BR * 36];   // 4.6 KB
    __shared__ int candidx[BR * CAP];                 // 7.2 KB
    __shared__ int cnt[BR];

    int tid   = threadIdx.x;
    int b     = blockIdx.y;
    int browg = blockIdx.x * BR;
    size_t bbase = (size_t)b * TT;

    int ig = tid >> 5;       // row group 0..7
    int j  = tid & 31;       // col scanner 0..31

    // stage the block's 32 row vectors (one float4 per thread)
    {
        int row = tid >> 3, part = tid & 7;
        *(float4*)&rowbuf[row * 36 + part * 4] =
            *(const float4*)&xnT[(bbase + browg + row) * CC + part * 4];
    }
    if (tid < BR) cnt[tid] = 0;

    float acc[RT][MT];

    // ---------------- pass A: per-thread row maxima ----------------
    float mseg[RT];
#pragma unroll
    for (int r = 0; r < RT; ++r) mseg[r] = NEGINF;

    for (int tt = 0; tt < NTILE; ++tt) {
        int ct0 = tt * BC;
        int ccn = (ct0 + BC <= TT) ? BC : (TT - ct0);
        int mm  = ccn >> 5;
        __syncthreads();
        for (int g = tid; g < ccn * 8; g += 256) {
            int col = g >> 3, part = g & 7;
            *(float4*)&colbuf[col * 36 + part * 4] =
                *(const float4*)&xnT[(bbase + ct0 + col) * CC + part * 4];
        }
        __syncthreads();

#pragma unroll
        for (int r = 0; r < RT; ++r)
#pragma unroll
            for (int m = 0; m < MT; ++m) acc[r][m] = 0.f;
#pragma unroll
        for (int cq = 0; cq < 8; ++cq) {
            float4 a[RT];
#pragma unroll
            for (int r = 0; r < RT; ++r)
                a[r] = *(const float4*)&rowbuf[(ig*RT + r) * 36 + cq * 4];
#pragma unroll
            for (int m = 0; m < MT; ++m) {
                float4 bv = *(const float4*)&colbuf[(j + 32*m) * 36 + cq * 4];
#pragma unroll
                for (int r = 0; r < RT; ++r) {
                    acc[r][m] = fmaf(a[r].x, bv.x, acc[r][m]);
                    acc[r][m] = fmaf(a[r].y, bv.y, acc[r][m]);
                    acc[r][m] = fmaf(a[r].z, bv.z, acc[r][m]);
                    acc[r][m] = fmaf(a[r].w, bv.w, acc[r][m]);
                }
            }
        }

#pragma unroll
        for (int r = 0; r < RT; ++r) {
            int rowg = browg + ig*RT + r;
#pragma unroll
            for (int m = 0; m < MT; ++m) {
                int col = ct0 + j + 32*m;
                float v = (col == rowg) ? NEGINF : acc[r][m];
                if (m < mm) mseg[r] = fmaxf(mseg[r], v);
            }
        }
    }

    // ---- theta: 9th-largest of 32 thread maxima, per row (shfl) ----
    int lane = tid & 63;
    unsigned long long halfmask = 0xFFFFFFFFull << (lane & 32);
    float th[RT];
#pragma unroll
    for (int r = 0; r < RT; ++r) {
        uint32_t key = f2s(mseg[r]);
        uint32_t nth = 0;
        for (int round = 0; round < 9; ++round) {
            uint32_t m = key;
#pragma unroll
            for (int d = 1; d < 32; d <<= 1) {
                uint32_t o = (uint32_t)__shfl_xor((int)m, d, 64);
                m = (o > m) ? o : m;
            }
            nth = m;                       // round 8 -> 9th largest
            unsigned long long bal = __ballot(key == m) & halfmask;
            int leader = __ffsll(bal) - 1;
            if (lane == leader) key = 0;   // consume current max
        }
        th[r] = s2f(nth) - EPS;
    }

    // ---------------- pass B: collect candidates >= theta ----------------
    for (int tt = 0; tt < NTILE; ++tt) {
        int ct0 = tt * BC;
        int ccn = (ct0 + BC <= TT) ? BC : (TT - ct0);
        int mm  = ccn >> 5;
        __syncthreads();
        for (int g = tid; g < ccn * 8; g += 256) {
            int col = g >> 3, part = g & 7;
            *(float4*)&colbuf[col * 36 + part * 4] =
                *(const float4*)&xnT[(bbase + ct0 + col) * CC + part * 4];
        }
        __syncthreads();

#pragma unroll
        for (int r = 0; r < RT; ++r)
#pragma unroll
            for (int m = 0; m < MT; ++m) acc[r][m] = 0.f;
#pragma unroll
        for (int cq = 0; cq < 8; ++cq) {
            float4 a[RT];
#pragma unroll
            for (int r = 0; r < RT; ++r)
                a[r] = *(const float4*)&rowbuf[(ig*RT + r) * 36 + cq * 4];
#pragma unroll
            for (int m = 0; m < MT; ++m) {
                float4 bv = *(const float4*)&colbuf[(j + 32*m) * 36 + cq * 4];
#pragma unroll
                for (int r = 0; r < RT; ++r) {
                    acc[r][m] = fmaf(a[r].x, bv.x, acc[r][m]);
                    acc[r][m] = fmaf(a[r].y, bv.y, acc[r][m]);
                    acc[r][m] = fmaf(a[r].z, bv.z, acc[r][m]);
                    acc[r][m] = fmaf(a[r].w, bv.w, acc[r][m]);
                }
            }
        }

#pragma unroll
        for (int r = 0; r < RT; ++r) {
            int rowl = ig*RT + r;
            int rowg = browg + rowl;
#pragma unroll
            for (int m = 0; m < MT; ++m) {
                int col = ct0 + j + 32*m;
                float v = (col == rowg) ? NEGINF : acc[r][m];
                if (m < mm && v >= th[r]) {
                    int n = atomicAdd(&cnt[rowl], 1);
                    if (n < CAP) candidx[rowl * CAP + n] = col;
                }
            }
        }
    }
    __syncthreads();

    // ---------------- pass C: fp64 exact re-rank ----------------
    double* scorebuf = (double*)colbuf;   // colbuf dead; 32*56*8 = 14336 B
    for (int g = tid; g < BR * CAP; g += 256) {
        int row  = g / CAP;
        int slot = g - row * CAP;
        int n = min(cnt[row], CAP);
        if (slot < n) {
            int s = candidx[row * CAP + slot];
            const float* xt = xfT + (bbase + browg + row) * CC;
            const float* xs = xfT + (bbase + s) * CC;
            double a2 = 0.0;
#pragma unroll
            for (int c = 0; c < CC; c += 4) {
                float4 xtv = *(const float4*)(xt + c);
                float4 xsv = *(const float4*)(xs + c);
                a2 = fma((double)xtv.x, (double)xsv.x, a2);
                a2 = fma((double)xtv.y, (double)xsv.y, a2);
                a2 = fma((double)xtv.z, (double)xsv.z, a2);
                a2 = fma((double)xtv.w, (double)xsv.w, a2);
            }
            scorebuf[row * CAP + slot] = a2 * invn[bbase + s];
        }
    }
    __syncthreads();

    if ((tid & 7) == 0) {
        int row = tid >> 3;
        int t   = browg + row;
        int n   = min(cnt[row], CAP);
        double v8[8]; int i8[8];
#pragma unroll
        for (int jj = 0; jj < 8; ++jj) { v8[jj] = -1.0e300; i8[jj] = 0x7FFFFFFF; }
        for (int sl = 0; sl < n; ++sl) {
            double scr = scorebuf[row * CAP + sl];
            int    idx = candidx[row * CAP + sl];
            bool better7 = (scr > v8[7]) || (scr == v8[7] && idx < i8[7]);
            if (better7) {
#pragma unroll
                for (int jj = 7; jj >= 1; --jj) {
                    bool up   = (scr > v8[jj-1]) || (scr == v8[jj-1] && idx < i8[jj-1]);
                    bool here = ((scr > v8[jj]) || (scr == v8[jj] && idx < i8[jj])) && !up;
                    v8[jj] = up ? v8[jj-1] : (here ? scr : v8[jj]);
                    i8[jj] = up ? i8[jj-1] : (here ? idx : i8[jj]);
                }
                bool top = (scr > v8[0]) || (scr == v8[0] && idx < i8[0]);
                if (top) { v8[0] = scr; i8[0] = idx; }
            }
        }
        int oi[9];
#pragma unroll
        for (int jj = 0; jj < 8; ++jj)
            oi[jj] = (i8[jj] == 0x7FFFFFFF) ? t : i8[jj];   // safety, never fires
        oi[8] = t;   // self (sim forced 1.1 -> always top-1)
        for (int a = 1; a < 9; ++a) {
            int kv = oi[a]; int jj = a - 1;
            while (jj >= 0 && oi[jj] > kv) { oi[jj+1] = oi[jj]; --jj; }
            oi[jj+1] = kv;
        }
        int* op = idxo + (bbase + t) * KK;
#pragma unroll
        for (int m = 0; m < 9; ++m) op[m] = oi[m];
    }
}

// ---------------------------------------------------------------------------
// Kernel 3: gather + conv1d(kernel=K, stride=K).
//   out[b][o][t] = sum_{k,c} W[o][c][k] * xfT[b][idx[b][t][k]][c]
// 4 t's share each wl read (LDS reads /4); per-t single acc chain preserves
// R3's validated summation order (k outer, c ascending).
// ---------------------------------------------------------------------------
__global__ __launch_bounds__(256) void gconv_kernel(
    const float* __restrict__ xfT, const int* __restrict__ idxi,
    const float* __restrict__ Wt, float* __restrict__ out)
{
    __shared__ float wl[288 * 65];
    __shared__ float ot[4][64 * 17];

    int tid = threadIdx.x;
    int b   = blockIdx.y;
    int t0  = blockIdx.x * 64;
    size_t bbase = (size_t)b * TT;

    for (int f = tid; f < OC * 288; f += 256) {
        int o  = f / 288;
        int ck = f - o * 288;
        wl[ck * 65 + o] = Wt[f];
    }
    __syncthreads();

    int w    = tid >> 6;
    int lane = tid & 63;        // = output channel o
    int tw0  = t0 + w * 16;

    for (int i0 = 0; i0 < 16; i0 += 4) {
        float a0 = 0.f, a1 = 0.f, a2 = 0.f, a3 = 0.f;
        const int* ip0 = idxi + (bbase + tw0 + i0) * KK;
#pragma unroll
        for (int k = 0; k < KK; ++k) {
            int s0 = __builtin_amdgcn_readfirstlane(ip0[0*KK + k]);
            int s1 = __builtin_amdgcn_readfirstlane(ip0[1*KK + k]);
            int s2 = __builtin_amdgcn_readfirstlane(ip0[2*KK + k]);
            int s3 = __builtin_amdgcn_readfirstlane(ip0[3*KK + k]);
            const float* c0 = xfT + (bbase + s0) * CC;
            const float* c1 = xfT + (bbase + s1) * CC;
            const float* c2 = xfT + (bbase + s2) * CC;
            const float* c3 = xfT + (bbase + s3) * CC;
#pragma unroll
            for (int c4 = 0; c4 < 8; ++c4) {
                float4 x0 = *(const float4*)(c0 + c4*4);
                float4 x1 = *(const float4*)(c1 + c4*4);
                float4 x2 = *(const float4*)(c2 + c4*4);
                float4 x3 = *(const float4*)(c3 + c4*4);
                float w0 = wl[((c4*4+0)*9 + k)*65 + lane];
                float w1 = wl[((c4*4+1)*9 + k)*65 + lane];
                float w2 = wl[((c4*4+2)*9 + k)*65 + lane];
                float w3 = wl[((c4*4+3)*9 + k)*65 + lane];
                a0 = fmaf(x0.x, w0, a0); a0 = fmaf(x0.y, w1, a0);
                a0 = fmaf(x0.z, w2, a0); a0 = fmaf(x0.w, w3, a0);
                a1 = fmaf(x1.x, w0, a1); a1 = fmaf(x1.y, w1, a1);
                a1 = fmaf(x1.z, w2, a1); a1 = fmaf(x1.w, w3, a1);
                a2 = fmaf(x2.x, w0, a2); a2 = fmaf(x2.y, w1, a2);
                a2 = fmaf(x2.z, w2, a2); a2 = fmaf(x2.w, w3, a2);
                a3 = fmaf(x3.x, w0, a3); a3 = fmaf(x3.y, w1, a3);
                a3 = fmaf(x3.z, w2, a3); a3 = fmaf(x3.w, w3, a3);
            }
        }
        ot[w][lane * 17 + i0 + 0] = a0;
        ot[w][lane * 17 + i0 + 1] = a1;
        ot[w][lane * 17 + i0 + 2] = a2;
        ot[w][lane * 17 + i0 + 3] = a3;
    }
    __syncthreads();

    for (int jj = 0; jj < 16; ++jj) {
        int fl = jj * 64 + lane;
        int o  = fl >> 4;
        int ii = fl & 15;
        out[((size_t)b * OC + o) * TT + tw0 + ii] = ot[w][o * 17 + ii];
    }
}

// ---------------------------------------------------------------------------
extern "C" void kernel_launch(void* const* d_in, const int* in_sizes, int n_in,
                              void* d_out, int out_size, void* d_ws, size_t ws_size,
                              hipStream_t stream)
{
    const float* x  = (const float*)d_in[0];   // [8][32][56][56]
    const float* Wt = (const float*)d_in[1];   // [64][32][9]
    float* out = (float*)d_out;                // [8][64][56][56]

    // workspace: xnT (fp32) | xfT (fp32) | invn (fp64) | idx (int)
    float*  xnT  = (float*)d_ws;
    float*  xfT  = xnT + (size_t)BB * TT * CC;
    double* invn = (double*)(xfT + (size_t)BB * TT * CC);
    int*    idw  = (int*)(invn + (size_t)BB * TT);

    dim3 g1((TT + 255) / 256, BB);
    norm_kernel<<<g1, 256, 0, stream>>>(x, xnT, xfT, invn);

    dim3 g2(TT / BR, BB);    // 98 x 8 = 784 blocks
    topk_kernel<<<g2, 256, 0, stream>>>(xnT, xfT, invn, idw);

    dim3 g3(TT / 64, BB);    // 49 x 8 = 392 blocks
    gconv_kernel<<<g3, 256, 0, stream>>>(xfT, idw, Wt, out);
}